// Round 13
// baseline (110.100 us; speedup 1.0000x reference)
//
#include <hip/hip_runtime.h>
#include <hip/hip_bf16.h>

#define NB 64
#define CD 128
#define LL 4096
#define NCHUNK 64
#define NBG 8          // blocks per n (512 l each)
#define NIT 4          // iterations per block (128 l each)

typedef __attribute__((ext_vector_type(8))) short short8;
typedef __attribute__((ext_vector_type(4))) float f32x4;
typedef __attribute__((ext_vector_type(16))) float f32x16;
typedef __attribute__((ext_vector_type(2))) unsigned u32x2;
typedef __attribute__((ext_vector_type(4))) unsigned u32x4;

#define LOG2E 1.4426950408889634f

// ws layout (bytes)
#define WT_OFF   0                                  // 3*128*128 bf16 = 96 KB
#define WSS_OFF  (1u<<20)
#define WSP_OFF  ((1u<<20) + NB*NBG*CD*4)
#define POOL_OFF ((1u<<20) + 2u*NB*NBG*CD*4)
#define WSQ_OFF  (8u<<20)                           // 64 MB bf16 sig(q), [n][d][l]

__device__ __forceinline__ unsigned short f2bf(float f) {
    union { float f; unsigned u; } v; v.f = f;
    unsigned r = v.u + 0x7FFFu + ((v.u >> 16) & 1u);
    return (unsigned short)(r >> 16);
}
__device__ __forceinline__ float bf2f(unsigned short h) {
    union { unsigned u; float f; } v; v.u = ((unsigned)h) << 16;
    return v.f;
}
__device__ __forceinline__ unsigned pack2(float lo, float hi) {
    union { __hip_bfloat162 h; unsigned u; } v;
    v.h = __float22bfloat162_rn(float2{lo, hi});   // v_cvt_pk_bf16_f32
    return v.u;
}
// asm load: issue point pinned; result cannot be remat'd
__device__ __forceinline__ f32x4 gload16f(const float* p) {
    f32x4 d;
    asm volatile("global_load_dwordx4 %0, %1, off"
                 : "=&v"(d) : "v"((unsigned long long)(uintptr_t)p));
    return d;
}

// W[t] is [C=128][D=128]; produce wt[t][d][c] = bf16(W[c][d])  (c contiguous)
__global__ void prep_wt(const float* __restrict__ Wq, const float* __restrict__ Wk,
                        const float* __restrict__ Wv, unsigned short* __restrict__ wt) {
    int t = blockIdx.x >> 7;
    int d = blockIdx.x & 127;
    const float* W = (t == 0) ? Wq : (t == 1) ? Wk : Wv;
    int c = threadIdx.x;
    wt[((size_t)t*CD + d)*CD + c] = f2bf(W[c*CD + d]);
}

// x-chunk LDS image: element (l,c) at byte 272*l + 16*((c>>3) ^ ((l>>2)&7)) + (c&7)*2
__device__ __forceinline__ void stage_x_write(char* bufx, int f, int cp, f32x4 lo, f32x4 hi) {
    char* base = bufx + (4*f)*272 + 16*((cp >> 2) ^ (f & 7)) + 4*(cp & 3);
#pragma unroll
    for (int j = 0; j < 4; ++j)
        *(unsigned*)(base + j*272) = pack2(lo[j], hi[j]);
}

// ---- pass 1: fused QKV GEMM, 32x32x16 MFMA, M=64 per wave, raw-barrier pipeline ----
// lds_w: row R = t*128+d (256 B); 16B-block b at byte 256*R + 16*(b ^ (R&7)).
// Wave ww: ch2 = ww>>2 (which 64-l chunk of the 128-l pair), ng = ww&3 (32-d group).
// Lane: u = lane&31, h = lane>>5. A rows l = 32*lt+u (lt=0,1); B col d = 32*ng+u.
// acc reg -> (l = 64*ch2 + 32*lt + (reg&3)+8*(reg>>2)+4*h, d)
__global__ __launch_bounds__(512) __attribute__((amdgpu_waves_per_eu(2, 2)))
void aft_qkv(const float* __restrict__ x, const unsigned short* __restrict__ wt,
             const float* __restrict__ bq, const float* __restrict__ bk,
             const float* __restrict__ bv,
             float* __restrict__ wsS, float* __restrict__ wsP,
             unsigned short* __restrict__ wsq) {
    __shared__ char lds_w[98304];
    __shared__ char lds_x[2 * 17408];        // 128-l pair, single-buffered
    __shared__ float red_s[4][32];
    __shared__ float red_p[4][32];
    const int tid = threadIdx.x;
    const int n = blockIdx.x >> 3;
    const int bg = blockIdx.x & 7;
    const int ww = tid >> 6, lane = tid & 63;
    const int u = lane & 31, h = lane >> 5;
    const int ch2 = ww >> 2, ng = ww & 3;
    const int d = 32*ng + u;
    const int f = tid & 15, tg = tid >> 4;   // staging: f = l-quad, tg = 0..31
    const int lbase = bg * (NIT * 128);
    const size_t xb0 = (size_t)n*CD*LL;

    // ---- stage all weights into LDS (once per block) ----
#pragma unroll
    for (int k = 0; k < 12; ++k) {
        int bi = tid + 512*k;
        u32x4 v = *(const u32x4*)((const char*)wt + (size_t)bi*16);
        *(u32x4*)(lds_w + 256*(bi >> 4) + 16*((bi & 15) ^ ((bi >> 4) & 7))) = v;
    }
    // ---- stage x pair 0 directly ----
#pragma unroll
    for (int c2 = 0; c2 < 2; ++c2)
#pragma unroll
        for (int itg = 0; itg < 2; ++itg) {
            int cp = tg + 32*itg;
            const float* p = x + xb0 + (size_t)(2*cp)*LL + lbase + 64*c2 + 4*f;
            f32x4 lo = *(const f32x4*)p;
            f32x4 hi = *(const f32x4*)(p + LL);
            stage_x_write(lds_x + c2*17408, f, cp, lo, hi);
        }
    const float bql = bq[d], bkl = bk[d], bvl = bv[d];
    float s_run = 0.f, p_run = 0.f;
    __syncthreads();

    const char* ax = lds_x + ch2*17408;
    const char* wbq = lds_w + 256*d;
    const int dsw = d & 7;

#pragma unroll 1
    for (int it = 0; it < NIT; ++it) {
        const int l0 = lbase + it*128;
        // ---- prefetch next 128-l pair (8 pinned loads) ----
        f32x4 pf0, pf1, pf2, pf3, pf4, pf5, pf6, pf7;
        if (it + 1 < NIT) {
            const float* pb = x + xb0 + l0 + 128 + 4*f;
            pf0 = gload16f(pb + (size_t)(2*tg     )*LL);
            pf1 = gload16f(pb + (size_t)(2*tg + 1 )*LL);
            pf2 = gload16f(pb + (size_t)(2*(tg+32)    )*LL);
            pf3 = gload16f(pb + (size_t)(2*(tg+32) + 1)*LL);
            pf4 = gload16f(pb + (size_t)(2*tg     )*LL + 64);
            pf5 = gload16f(pb + (size_t)(2*tg + 1 )*LL + 64);
            pf6 = gload16f(pb + (size_t)(2*(tg+32)    )*LL + 64);
            pf7 = gload16f(pb + (size_t)(2*(tg+32) + 1)*LL + 64);
        }
        // ---- compute: 8 k-steps; 5 LDS reads feed 6 MFMAs ----
        f32x16 aq[2], ak[2], av[2];
#pragma unroll
        for (int lt = 0; lt < 2; ++lt) {
            aq[lt] = (f32x16){0,0,0,0,0,0,0,0,0,0,0,0,0,0,0,0};
            ak[lt] = (f32x16){0,0,0,0,0,0,0,0,0,0,0,0,0,0,0,0};
            av[lt] = (f32x16){0,0,0,0,0,0,0,0,0,0,0,0,0,0,0,0};
        }
#pragma unroll
        for (int kk = 0; kk < 8; ++kk) {
            const int cb = 2*kk + h;
            short8 a0  = *(const short8*)(ax + 272*(u     ) + 16*(cb ^ ((u >> 2) & 7)));
            short8 a1  = *(const short8*)(ax + 272*(u + 32) + 16*(cb ^ ((u >> 2) & 7)));
            short8 wqf = *(const short8*)(wbq           + 16*(cb ^ dsw));
            short8 wkf = *(const short8*)(wbq + 32768   + 16*(cb ^ dsw));
            short8 wvf = *(const short8*)(wbq + 65536   + 16*(cb ^ dsw));
            aq[0] = __builtin_amdgcn_mfma_f32_32x32x16_bf16(a0, wqf, aq[0], 0,0,0);
            ak[0] = __builtin_amdgcn_mfma_f32_32x32x16_bf16(a0, wkf, ak[0], 0,0,0);
            av[0] = __builtin_amdgcn_mfma_f32_32x32x16_bf16(a0, wvf, av[0], 0,0,0);
            aq[1] = __builtin_amdgcn_mfma_f32_32x32x16_bf16(a1, wqf, aq[1], 0,0,0);
            ak[1] = __builtin_amdgcn_mfma_f32_32x32x16_bf16(a1, wkf, ak[1], 0,0,0);
            av[1] = __builtin_amdgcn_mfma_f32_32x32x16_bf16(a1, wvf, av[1], 0,0,0);
        }
        // ---- epilogue: (s,p) fold + sigmoid(q) -> wsq (8 u32x2 stores) ----
#pragma unroll
        for (int lt = 0; lt < 2; ++lt) {
#pragma unroll
            for (int grp = 0; grp < 4; ++grp) {
                float sg[4];
#pragma unroll
                for (int e = 0; e < 4; ++e) {
                    const int reg = 4*grp + e;
                    float ex = __builtin_amdgcn_exp2f((ak[lt][reg] + bkl) * LOG2E);
                    s_run += ex;
                    p_run += ex * (av[lt][reg] + bvl);
                    float q2 = (aq[lt][reg] + bql) * LOG2E;
                    sg[e] = __builtin_amdgcn_rcpf(1.f + __builtin_amdgcn_exp2f(-q2));
                }
                u32x2 val = { pack2(sg[0], sg[1]), pack2(sg[2], sg[3]) };
                *(u32x2*)(wsq + ((size_t)n*CD + d)*LL
                          + l0 + 64*ch2 + 32*lt + 8*grp + 4*h) = val;
            }
        }
        // ---- pipeline turn: wait the 8 loads (stores float), swap buffer in place ----
        if (it + 1 < NIT) {
            asm volatile("s_waitcnt vmcnt(8)" ::: "memory");
            __builtin_amdgcn_sched_barrier(0);
            __builtin_amdgcn_s_barrier();                  // all waves done reading
            __builtin_amdgcn_sched_barrier(0);
            stage_x_write(lds_x,         f, tg,      pf0, pf1);
            stage_x_write(lds_x,         f, tg + 32, pf2, pf3);
            stage_x_write(lds_x + 17408, f, tg,      pf4, pf5);
            stage_x_write(lds_x + 17408, f, tg + 32, pf6, pf7);
            asm volatile("s_waitcnt lgkmcnt(0)" ::: "memory");
            __builtin_amdgcn_sched_barrier(0);
            __builtin_amdgcn_s_barrier();                  // buffer ready
            __builtin_amdgcn_sched_barrier(0);
        }
    }

    // ---- block (s,p) reduce: fold h, then the 2 ch2 waves per d-group ----
    s_run += __shfl_xor(s_run, 32, 64);
    p_run += __shfl_xor(p_run, 32, 64);
    if (ch2 == 1 && h == 0) { red_s[ng][u] = s_run; red_p[ng][u] = p_run; }
    __syncthreads();
    if (ch2 == 0 && h == 0) {
        size_t idx = ((size_t)n*NBG + bg)*CD + d;
        wsS[idx] = s_run + red_s[ng][u];
        wsP[idx] = p_run + red_p[ng][u];
    }
}

// ---------------- pass 2: combine partials -> pooled[n][d] ----------------
__global__ void aft_pass2(const float* __restrict__ wsS, const float* __restrict__ wsP,
                          float* __restrict__ pooled) {
    int n = blockIdx.x, d = threadIdx.x;
    float s = 0.f, p = 0.f;
    for (int b = 0; b < NBG; ++b) {
        size_t idx = ((size_t)n*NBG + b)*CD + d;
        s += wsS[idx];
        p += wsP[idx];
    }
    pooled[(size_t)n*CD + d] = p / s;
}

// ---- pass 3: out[n][d][l] = bf2f(wsq[n][d][l]) * pooled[n][d], pure streaming ----
__global__ __launch_bounds__(256)
void aft_pass3(const unsigned short* __restrict__ wsq, const float* __restrict__ pooled,
               float* __restrict__ out) {
    const int b = blockIdx.x;
    const int n = b >> 8;
    const int d = (b >> 1) & 127;
    const int half = b & 1;
    const float pl = pooled[(size_t)n*CD + d];
    const size_t base = ((size_t)n*CD + d)*LL + half*2048 + threadIdx.x*8;
    short8 v = *(const short8*)(wsq + base);
    f32x4 o0, o1;
#pragma unroll
    for (int j = 0; j < 4; ++j) {
        o0[j] = bf2f((unsigned short)v[j]) * pl;
        o1[j] = bf2f((unsigned short)v[4+j]) * pl;
    }
    *(f32x4*)(out + base) = o0;
    *(f32x4*)(out + base + 4) = o1;
}

extern "C" void kernel_launch(void* const* d_in, const int* in_sizes, int n_in,
                              void* d_out, int out_size, void* d_ws, size_t ws_size,
                              hipStream_t stream) {
    const float* x  = (const float*)d_in[0];
    const float* Wq = (const float*)d_in[1];
    const float* bq = (const float*)d_in[2];
    const float* Wk = (const float*)d_in[3];
    const float* bk = (const float*)d_in[4];
    const float* Wv = (const float*)d_in[5];
    const float* bv = (const float*)d_in[6];
    float* out = (float*)d_out;
    char* ws = (char*)d_ws;
    unsigned short* wt = (unsigned short*)(ws + WT_OFF);
    float* wsS = (float*)(ws + WSS_OFF);
    float* wsP = (float*)(ws + WSP_OFF);
    float* pooled = (float*)(ws + POOL_OFF);
    unsigned short* wsq = (unsigned short*)(ws + WSQ_OFF);

    prep_wt<<<384, 128, 0, stream>>>(Wq, Wk, Wv, wt);
    aft_qkv<<<NB * NBG, 512, 0, stream>>>(x, wt, bq, bk, bv, wsS, wsP, wsq);
    aft_pass2<<<NB, CD, 0, stream>>>(wsS, wsP, pooled);
    aft_pass3<<<NB * CD * 2, 256, 0, stream>>>(wsq, pooled, out);
}